// Round 1
// baseline (7730.357 us; speedup 1.0000x reference)
//
#include <hip/hip_runtime.h>
#include <hip/hip_bf16.h>
#include <math.h>

#define NN 20000
#define NE 320000
#define NG 128
#define DD 64
#define FA 92
#define FF 128

__device__ __forceinline__ float sp_(float x) {
    return fmaxf(x, 0.f) + log1pf(__expf(-fabsf(x)));
}
__device__ __forceinline__ float sig_(float x) {
    return 1.f / (1.f + __expf(-x));
}

// ---------------- embedding: h = af @ emb_W + emb_b ----------------
__global__ __launch_bounds__(256) void embed_k(const float* __restrict__ af,
                                               const float* __restrict__ W,
                                               const float* __restrict__ b,
                                               float* __restrict__ h) {
    __shared__ float Ws[FA * DD]; // 23552 B
    for (int i = threadIdx.x * 4; i < FA * DD; i += 256 * 4)
        *(float4*)&Ws[i] = *(const float4*)&W[i];
    __syncthreads();
    int n = blockIdx.x * 256 + threadIdx.x;
    if (n >= NN) return;
    float acc[DD];
#pragma unroll
    for (int j = 0; j < DD; ++j) acc[j] = b[j];
    const float* row = af + (size_t)n * FA;
#pragma unroll 1
    for (int k4 = 0; k4 < FA / 4; ++k4) {
        float4 z = *(const float4*)(row + k4 * 4);
#pragma unroll
        for (int kk = 0; kk < 4; ++kk) {
            float a = ((const float*)&z)[kk];
            const float* wr = &Ws[(k4 * 4 + kk) * DD];
#pragma unroll
            for (int j = 0; j < DD; j += 4) {
                float4 w = *(const float4*)(wr + j);
                acc[j + 0] += a * w.x; acc[j + 1] += a * w.y;
                acc[j + 2] += a * w.z; acc[j + 3] += a * w.w;
            }
        }
    }
    float* o = h + (size_t)n * DD;
#pragma unroll
    for (int j = 0; j < DD; j += 4) {
        float4 v; v.x = acc[j]; v.y = acc[j + 1]; v.z = acc[j + 2]; v.w = acc[j + 3];
        *(float4*)(o + j) = v;
    }
}

// ---------------- CSR build ----------------
__global__ void cnt_edges_k(const int* __restrict__ dst, int* __restrict__ cnt) {
    int e = blockIdx.x * 256 + threadIdx.x;
    if (e < NE) atomicAdd(&cnt[dst[e]], 1);
}

__global__ __launch_bounds__(1024) void csr_scan_k(const int* __restrict__ cnt,
                                                   int* __restrict__ off,
                                                   int* __restrict__ cur) {
    __shared__ int part[1024];
    int t = threadIdx.x;
    int base = t * 20;
    int s = 0;
    for (int i = 0; i < 20; ++i) { int idx = base + i; if (idx < NN) s += cnt[idx]; }
    part[t] = s;
    __syncthreads();
    for (int ofs = 1; ofs < 1024; ofs <<= 1) {
        int v = (t >= ofs) ? part[t - ofs] : 0;
        __syncthreads();
        part[t] += v;
        __syncthreads();
    }
    int run = (t == 0) ? 0 : part[t - 1];
    for (int i = 0; i < 20; ++i) {
        int idx = base + i;
        if (idx < NN) { off[idx] = run; cur[idx] = run; run += cnt[idx]; }
    }
    if (t == 1023) off[NN] = run;
}

__global__ void fill_edges_k(const int* __restrict__ dst, int* __restrict__ cur,
                             int* __restrict__ lst) {
    int e = blockIdx.x * 256 + threadIdx.x;
    if (e < NE) {
        int p = atomicAdd(&cur[dst[e]], 1);
        lst[p] = e;
    }
}

// ---------------- edge GEMM: pre = [h[src],h[dst],rbf(bond)] @ W, + column stats ----------------
__global__ __launch_bounds__(256, 2) void edge_gemm_k(const float* __restrict__ h,
                                                      const float* __restrict__ W, // [160*64]
                                                      const float* __restrict__ bond,
                                                      const int* __restrict__ src,
                                                      const int* __restrict__ dst,
                                                      float* __restrict__ pre,
                                                      float* __restrict__ ssum,
                                                      float* __restrict__ ssq) {
    __shared__ float Ws[160 * DD]; // 40 KB
    for (int i = threadIdx.x * 4; i < 160 * DD; i += 256 * 4)
        *(float4*)&Ws[i] = *(const float4*)&W[i];
    __syncthreads();

    const int e0 = blockIdx.x * 512 + threadIdx.x;
    const int e1 = e0 + 256;

    float acc0[DD], acc1[DD];
#pragma unroll
    for (int j = 0; j < DD; ++j) { acc0[j] = 0.f; acc1[j] = 0.f; }

    const float* r0 = h + (size_t)src[e0] * DD;
    const float* r1 = h + (size_t)src[e1] * DD;
#pragma unroll 1
    for (int k4 = 0; k4 < 16; ++k4) {
        float4 z0 = *(const float4*)(r0 + k4 * 4);
        float4 z1 = *(const float4*)(r1 + k4 * 4);
        const float* wb = &Ws[k4 * 4 * DD];
#pragma unroll
        for (int kk = 0; kk < 4; ++kk) {
            float a0 = ((const float*)&z0)[kk];
            float a1 = ((const float*)&z1)[kk];
            const float* wr = wb + kk * DD;
#pragma unroll
            for (int j = 0; j < DD; j += 4) {
                float4 w = *(const float4*)(wr + j);
                acc0[j + 0] += a0 * w.x; acc0[j + 1] += a0 * w.y;
                acc0[j + 2] += a0 * w.z; acc0[j + 3] += a0 * w.w;
                acc1[j + 0] += a1 * w.x; acc1[j + 1] += a1 * w.y;
                acc1[j + 2] += a1 * w.z; acc1[j + 3] += a1 * w.w;
            }
        }
    }
    r0 = h + (size_t)dst[e0] * DD;
    r1 = h + (size_t)dst[e1] * DD;
#pragma unroll 1
    for (int k4 = 0; k4 < 16; ++k4) {
        float4 z0 = *(const float4*)(r0 + k4 * 4);
        float4 z1 = *(const float4*)(r1 + k4 * 4);
        const float* wb = &Ws[(64 + k4 * 4) * DD];
#pragma unroll
        for (int kk = 0; kk < 4; ++kk) {
            float a0 = ((const float*)&z0)[kk];
            float a1 = ((const float*)&z1)[kk];
            const float* wr = wb + kk * DD;
#pragma unroll
            for (int j = 0; j < DD; j += 4) {
                float4 w = *(const float4*)(wr + j);
                acc0[j + 0] += a0 * w.x; acc0[j + 1] += a0 * w.y;
                acc0[j + 2] += a0 * w.z; acc0[j + 3] += a0 * w.w;
                acc1[j + 0] += a1 * w.x; acc1[j + 1] += a1 * w.y;
                acc1[j + 2] += a1 * w.z; acc1[j + 3] += a1 * w.w;
            }
        }
    }
    // RBF phase: rbf_k = exp(-gamma*(d - 8k/31)^2), gamma = 31/8
    float d0 = bond[e0], d1 = bond[e1];
#pragma unroll 1
    for (int k = 0; k < 32; ++k) {
        float c = (float)k * (8.0f / 31.0f);
        float u0 = d0 - c, u1 = d1 - c;
        float a0 = __expf(-3.875f * u0 * u0);
        float a1 = __expf(-3.875f * u1 * u1);
        const float* wr = &Ws[(128 + k) * DD];
#pragma unroll
        for (int j = 0; j < DD; j += 4) {
            float4 w = *(const float4*)(wr + j);
            acc0[j + 0] += a0 * w.x; acc0[j + 1] += a0 * w.y;
            acc0[j + 2] += a0 * w.z; acc0[j + 3] += a0 * w.w;
            acc1[j + 0] += a1 * w.x; acc1[j + 1] += a1 * w.y;
            acc1[j + 2] += a1 * w.z; acc1[j + 3] += a1 * w.w;
        }
    }

    float* o0 = pre + (size_t)e0 * DD;
    float* o1 = pre + (size_t)e1 * DD;
#pragma unroll
    for (int j = 0; j < DD; j += 4) {
        float4 v0; v0.x = acc0[j]; v0.y = acc0[j + 1]; v0.z = acc0[j + 2]; v0.w = acc0[j + 3];
        float4 v1; v1.x = acc1[j]; v1.y = acc1[j + 1]; v1.z = acc1[j + 2]; v1.w = acc1[j + 3];
        *(float4*)(o0 + j) = v0;
        *(float4*)(o1 + j) = v1;
    }

    // column statistics: wave-level butterfly reduce, one atomic pair per wave per column
    int lane = threadIdx.x & 63;
#pragma unroll
    for (int j = 0; j < DD; ++j) {
        float s = acc0[j] + acc1[j];
        float q = acc0[j] * acc0[j] + acc1[j] * acc1[j];
#pragma unroll
        for (int mk = 32; mk >= 1; mk >>= 1) {
            s += __shfl_xor(s, mk, 64);
            q += __shfl_xor(q, mk, 64);
        }
        if (lane == 0) {
            unsafeAtomicAdd(&ssum[j], s);
            unsafeAtomicAdd(&ssq[j], q);
        }
    }
}

// ---------------- finalize BN coefficients for gate/update ----------------
__global__ void fin_iu_k(const float* __restrict__ stats,
                         const float* __restrict__ gi, const float* __restrict__ bbi,
                         const float* __restrict__ gu, const float* __restrict__ bbu,
                         float* __restrict__ coeff) {
    int j = threadIdx.x; // 64
    const float invE = 1.f / (float)NE;
    float muI = stats[j] * invE;
    float varI = stats[64 + j] * invE - muI * muI;
    float sI = gi[j] * rsqrtf(varI + 1e-5f);
    coeff[j] = sI;
    coeff[64 + j] = bbi[j] - muI * sI;
    float muU = stats[128 + j] * invE;
    float varU = stats[192 + j] * invE - muU * muU;
    float sU = gu[j] * rsqrtf(varU + 1e-5f);
    coeff[128 + j] = sU;
    coeff[192 + j] = bbu[j] - muU * sU;
}

// ---------------- apply gate/update + CSR segment sum into m, + m column stats ----------------
__global__ __launch_bounds__(256) void apply_csr_k(const float* __restrict__ preI,
                                                   const float* __restrict__ preU,
                                                   const float* __restrict__ coeff,
                                                   const int* __restrict__ off,
                                                   const int* __restrict__ lst,
                                                   float* __restrict__ m,
                                                   float* __restrict__ msum,
                                                   float* __restrict__ msq) {
    int lane = threadIdx.x & 63;
    int wid = (blockIdx.x * blockDim.x + threadIdx.x) >> 6;
    int nw = (gridDim.x * blockDim.x) >> 6;
    float sI = coeff[lane], tI = coeff[64 + lane];
    float sU = coeff[128 + lane], tU = coeff[192 + lane];
    float accS = 0.f, accQ = 0.f;
    for (int n = wid; n < NN; n += nw) {
        int b = off[n], e = off[n + 1];
        float acc = 0.f;
        for (int i = b; i < e; ++i) {
            int eid = lst[i];
            float xi = preI[(size_t)eid * DD + lane] * sI + tI;
            float xu = preU[(size_t)eid * DD + lane] * sU + tU;
            acc += sig_(xi) * sp_(xu);
        }
        m[(size_t)n * DD + lane] = acc;
        accS += acc;
        accQ += acc * acc;
    }
    unsafeAtomicAdd(&msum[lane], accS);
    unsafeAtomicAdd(&msq[lane], accQ);
}

__global__ void fin_n_k(const float* __restrict__ msum, const float* __restrict__ msq,
                        const float* __restrict__ gn, const float* __restrict__ bbn,
                        float* __restrict__ coeffN) {
    int j = threadIdx.x; // 64
    const float invN = 1.f / (float)NN;
    float mu = msum[j] * invN;
    float var = msq[j] * invN - mu * mu;
    float s = gn[j] * rsqrtf(var + 1e-5f);
    coeffN[j] = s;
    coeffN[64 + j] = bbn[j] - mu * s;
}

// ---------------- h = sp(h + bn(m)) ----------------
__global__ void h_update_k(float* __restrict__ h, const float* __restrict__ m,
                           const float* __restrict__ coeffN) {
    int i = blockIdx.x * 256 + threadIdx.x;
    if (i >= NN * DD) return;
    int j = i & 63;
    float v = h[i] + m[i] * coeffN[j] + coeffN[64 + j];
    h[i] = sp_(v);
}

// ---------------- pooling ----------------
__global__ void pool_k(const float* __restrict__ h, const int* __restrict__ gid,
                       float* __restrict__ pool) {
    int i = blockIdx.x * 256 + threadIdx.x;
    if (i >= NN * DD) return;
    int n = i >> 6;
    unsafeAtomicAdd(&pool[(size_t)gid[n] * DD + (i & 63)], h[i]);
}

__global__ void cnt_graph_k(const int* __restrict__ gid, float* __restrict__ pcnt) {
    int n = blockIdx.x * 256 + threadIdx.x;
    if (n < NN) unsafeAtomicAdd(&pcnt[gid[n]], 1.f);
}

// ---------------- head: sp, fc+sp, sp, out ----------------
__global__ __launch_bounds__(128) void head_k(const float* __restrict__ pool,
                                              const float* __restrict__ pcnt,
                                              const float* __restrict__ fcW,
                                              const float* __restrict__ fcb,
                                              const float* __restrict__ oW,
                                              const float* __restrict__ ob,
                                              float* __restrict__ out) {
    int g = blockIdx.x;
    int t = threadIdx.x; // 128
    __shared__ float feats[DD];
    __shared__ float red[FF];
    if (t < DD) {
        float c = fmaxf(pcnt[g], 1.f);
        feats[t] = sp_(pool[(size_t)g * DD + t] / c);
    }
    __syncthreads();
    float a = fcb[t];
#pragma unroll 1
    for (int j = 0; j < DD; ++j) a += feats[j] * fcW[j * FF + t];
    float y = sp_(sp_(a));
    red[t] = y * oW[t];
    __syncthreads();
    for (int s2 = 64; s2 >= 1; s2 >>= 1) {
        if (t < s2) red[t] += red[t + s2];
        __syncthreads();
    }
    if (t == 0) out[g] = red[0] + ob[0];
}

extern "C" void kernel_launch(void* const* d_in, const int* in_sizes, int n_in,
                              void* d_out, int out_size, void* d_ws, size_t ws_size,
                              hipStream_t stream) {
    const float* af   = (const float*)d_in[0];
    const float* bond = (const float*)d_in[1];
    const int*   src  = (const int*)d_in[2];
    const int*   dst  = (const int*)d_in[3];
    const int*   gid  = (const int*)d_in[4];
    const float* embW = (const float*)d_in[5];
    const float* embB = (const float*)d_in[6];
    const float* Wi   = (const float*)d_in[7];
    const float* gi   = (const float*)d_in[9];
    const float* bbi  = (const float*)d_in[10];
    const float* Wu   = (const float*)d_in[11];
    const float* gu   = (const float*)d_in[13];
    const float* bbu  = (const float*)d_in[14];
    const float* gn   = (const float*)d_in[15];
    const float* bbn  = (const float*)d_in[16];
    const float* fcW  = (const float*)d_in[17];
    const float* fcb  = (const float*)d_in[18];
    const float* oW   = (const float*)d_in[19];
    const float* ob   = (const float*)d_in[20];
    float* out = (float*)d_out;

    char* ws = (char*)d_ws;
    size_t off = 0;
    auto take = [&](size_t bytes) {
        size_t o = off;
        off += (bytes + 255) & ~(size_t)255;
        return o;
    };
    float* h     = (float*)(ws + take((size_t)NN * DD * 4));
    float* m     = (float*)(ws + take((size_t)NN * DD * 4));
    float* preI  = (float*)(ws + take((size_t)NE * DD * 4));
    float* preU  = (float*)(ws + take((size_t)NE * DD * 4));
    float* stats = (float*)(ws + take(512 * 4)); // [sumI,sqI,sumU,sqU,msum,msq] = 384 used
    float* coeff = (float*)(ws + take(512 * 4)); // [sI,tI,sU,tU | sN,tN] = 384 used
    float* pool  = (float*)(ws + take((size_t)NG * DD * 4)); // 32768 B
    float* pcnt  = (float*)(ws + take((size_t)NG * 4));      // 512 B padded
    int* ecount  = (int*)(ws + take((size_t)NN * 4));
    int* eoff    = (int*)(ws + take((size_t)(NN + 1) * 4));
    int* ecur    = (int*)(ws + take((size_t)NN * 4));
    int* elist   = (int*)(ws + take((size_t)NE * 4));

    // zero: pool (32768) + pcnt (512 incl pad) + ecount (80000) — contiguous
    hipMemsetAsync((void*)pool, 0, 32768 + 512 + (size_t)NN * 4, stream);

    embed_k<<<(NN + 255) / 256, 256, 0, stream>>>(af, embW, embB, h);

    cnt_edges_k<<<(NE + 255) / 256, 256, 0, stream>>>(dst, ecount);
    csr_scan_k<<<1, 1024, 0, stream>>>(ecount, eoff, ecur);
    fill_edges_k<<<(NE + 255) / 256, 256, 0, stream>>>(dst, ecur, elist);

    for (int l = 0; l < 3; ++l) {
        hipMemsetAsync((void*)stats, 0, 384 * 4, stream);
        edge_gemm_k<<<NE / 512, 256, 0, stream>>>(h, Wi + (size_t)l * 160 * DD, bond, src, dst,
                                                  preI, stats, stats + 64);
        edge_gemm_k<<<NE / 512, 256, 0, stream>>>(h, Wu + (size_t)l * 160 * DD, bond, src, dst,
                                                  preU, stats + 128, stats + 192);
        fin_iu_k<<<1, 64, 0, stream>>>(stats, gi + l * DD, bbi + l * DD, gu + l * DD, bbu + l * DD,
                                       coeff);
        apply_csr_k<<<320, 256, 0, stream>>>(preI, preU, coeff, eoff, elist, m, stats + 256,
                                             stats + 320);
        fin_n_k<<<1, 64, 0, stream>>>(stats + 256, stats + 320, gn + l * DD, bbn + l * DD,
                                      coeff + 256);
        h_update_k<<<(NN * DD + 255) / 256, 256, 0, stream>>>(h, m, coeff + 256);
    }

    pool_k<<<(NN * DD + 255) / 256, 256, 0, stream>>>(h, gid, pool);
    cnt_graph_k<<<(NN + 255) / 256, 256, 0, stream>>>(gid, pcnt);
    head_k<<<NG, 128, 0, stream>>>(pool, pcnt, fcW, fcb, oW, ob, out);
}

// Round 2
// 1136.608 us; speedup vs baseline: 6.8013x; 6.8013x over previous
//
#include <hip/hip_runtime.h>
#include <hip/hip_bf16.h>
#include <math.h>

#define NN 20000
#define NE 320000
#define NG 128
#define DD 64
#define FA 92
#define FF 128

typedef __attribute__((ext_vector_type(8))) short bf16x8;
typedef __attribute__((ext_vector_type(4))) float f32x4;

__device__ __forceinline__ float sp_(float x) {
    return fmaxf(x, 0.f) + log1pf(__expf(-fabsf(x)));
}
__device__ __forceinline__ float sig_(float x) {
    return 1.f / (1.f + __expf(-x));
}
__device__ __forceinline__ unsigned short f2b(float x) {
    __hip_bfloat16 b = __float2bfloat16(x);
    return *reinterpret_cast<unsigned short*>(&b);
}

// ---------------- embedding: h = af @ emb_W + emb_b (fp32 + bf16 copy) ----------------
__global__ __launch_bounds__(256) void embed_k(const float* __restrict__ af,
                                               const float* __restrict__ W,
                                               const float* __restrict__ b,
                                               float* __restrict__ h,
                                               unsigned short* __restrict__ hb) {
    __shared__ float Ws[FA * DD]; // 23552 B
    for (int i = threadIdx.x * 4; i < FA * DD; i += 256 * 4)
        *(float4*)&Ws[i] = *(const float4*)&W[i];
    __syncthreads();
    int n = blockIdx.x * 256 + threadIdx.x;
    if (n >= NN) return;
    float acc[DD];
#pragma unroll
    for (int j = 0; j < DD; ++j) acc[j] = b[j];
    const float* row = af + (size_t)n * FA;
#pragma unroll 1
    for (int k4 = 0; k4 < FA / 4; ++k4) {
        float4 z = *(const float4*)(row + k4 * 4);
#pragma unroll
        for (int kk = 0; kk < 4; ++kk) {
            float a = ((const float*)&z)[kk];
            const float* wr = &Ws[(k4 * 4 + kk) * DD];
#pragma unroll
            for (int j = 0; j < DD; j += 4) {
                float4 w = *(const float4*)(wr + j);
                acc[j + 0] += a * w.x; acc[j + 1] += a * w.y;
                acc[j + 2] += a * w.z; acc[j + 3] += a * w.w;
            }
        }
    }
    float* o = h + (size_t)n * DD;
    unsigned short* ob = hb + (size_t)n * DD;
#pragma unroll
    for (int j = 0; j < DD; j += 4) {
        float4 v; v.x = acc[j]; v.y = acc[j + 1]; v.z = acc[j + 2]; v.w = acc[j + 3];
        *(float4*)(o + j) = v;
    }
#pragma unroll
    for (int j = 0; j < DD; ++j) ob[j] = f2b(acc[j]);
}

// ---------------- RBF bf16 precompute: rbfb[e][32] ----------------
__global__ void rbf_k(const float* __restrict__ bond, unsigned short* __restrict__ rbfb) {
    int e = blockIdx.x * 256 + threadIdx.x;
    if (e >= NE) return;
    float d = bond[e];
    unsigned short tmp[32];
#pragma unroll
    for (int k = 0; k < 32; ++k) {
        float c = (float)k * (8.0f / 31.0f);
        float u = d - c;
        tmp[k] = f2b(__expf(-3.875f * u * u));
    }
#pragma unroll
    for (int q = 0; q < 4; ++q)
        *(bf16x8*)&rbfb[(size_t)e * 32 + q * 8] = *(const bf16x8*)&tmp[q * 8];
}

// ---------------- weight fragment prep: Wf[l][g][kt][nf][lane][i] bf16 ----------------
// element = W[k = kt*32 + 8*(lane>>4) + i][col = nf*16 + (lane&15)]
__global__ void prep_wf_k(const float* __restrict__ Wi, const float* __restrict__ Wu,
                          unsigned short* __restrict__ Wf) {
    int b = blockIdx.x;          // 0..5 : layer*2 + gate
    int l = b >> 1, g = b & 1;
    const float* W = (g ? Wu : Wi) + (size_t)l * 160 * DD;
    for (int f = threadIdx.x; f < 10240; f += 256) {
        int i = f & 7;
        int lane = (f >> 3) & 63;
        int nf = (f >> 9) & 3;
        int kt = f >> 11;
        int k = kt * 32 + 8 * (lane >> 4) + i;
        int col = nf * 16 + (lane & 15);
        Wf[(size_t)b * 10240 + f] = f2b(W[k * DD + col]);
    }
}

// ---------------- CSR build ----------------
__global__ void cnt_edges_k(const int* __restrict__ dst, int* __restrict__ cnt) {
    int e = blockIdx.x * 256 + threadIdx.x;
    if (e < NE) atomicAdd(&cnt[dst[e]], 1);
}

__global__ __launch_bounds__(1024) void csr_scan_k(const int* __restrict__ cnt,
                                                   int* __restrict__ off,
                                                   int* __restrict__ cur) {
    __shared__ int part[1024];
    int t = threadIdx.x;
    int base = t * 20;
    int s = 0;
    for (int i = 0; i < 20; ++i) { int idx = base + i; if (idx < NN) s += cnt[idx]; }
    part[t] = s;
    __syncthreads();
    for (int ofs = 1; ofs < 1024; ofs <<= 1) {
        int v = (t >= ofs) ? part[t - ofs] : 0;
        __syncthreads();
        part[t] += v;
        __syncthreads();
    }
    int run = (t == 0) ? 0 : part[t - 1];
    for (int i = 0; i < 20; ++i) {
        int idx = base + i;
        if (idx < NN) { off[idx] = run; cur[idx] = run; run += cnt[idx]; }
    }
    if (t == 1023) off[NN] = run;
}

__global__ void fill_edges_k(const int* __restrict__ dst, int* __restrict__ cur,
                             int* __restrict__ lst) {
    int e = blockIdx.x * 256 + threadIdx.x;
    if (e < NE) {
        int p = atomicAdd(&cur[dst[e]], 1);
        lst[p] = e;
    }
}

// ---------------- fused edge GEMM (bf16 MFMA): preI & preU + column stats ----------------
// A tile: 16 edges x K=160 (z = [hb[src] | hb[dst] | rbf]); B: Wf fragments in LDS.
__global__ __launch_bounds__(256) void edge_mfma_k(const unsigned short* __restrict__ hb,
                                                   const unsigned short* __restrict__ rbfb,
                                                   const unsigned short* __restrict__ Wf, // [2][5][4][64][8] this layer
                                                   const int* __restrict__ src,
                                                   const int* __restrict__ dst,
                                                   float* __restrict__ preI,
                                                   float* __restrict__ preU,
                                                   float* __restrict__ stats) {
    __shared__ bf16x8 WfS[2560]; // 40960 B : [gate][kt][nf][lane]
    {
        const bf16x8* Wf8 = (const bf16x8*)Wf;
        for (int i = threadIdx.x; i < 2560; i += 256) WfS[i] = Wf8[i];
    }
    __syncthreads();

    const int lane = threadIdx.x & 63;
    const int r = lane & 15;   // A row within tile / D col
    const int c = lane >> 4;   // k-chunk / D row group
    const int wid = (blockIdx.x * 256 + threadIdx.x) >> 6;
    const int nwaves = (gridDim.x * 256) >> 6;

    float sI[4] = {0.f, 0.f, 0.f, 0.f}, qI[4] = {0.f, 0.f, 0.f, 0.f};
    float sU[4] = {0.f, 0.f, 0.f, 0.f}, qU[4] = {0.f, 0.f, 0.f, 0.f};

    for (int tile = wid; tile < NE / 16; tile += nwaves) {
        const int e0 = tile * 16;
        const int es = src[e0 + r];
        const int ed = dst[e0 + r];

        bf16x8 a0 = *(const bf16x8*)(hb + (size_t)es * DD + c * 8);
        bf16x8 a1 = *(const bf16x8*)(hb + (size_t)es * DD + 32 + c * 8);
        bf16x8 a2 = *(const bf16x8*)(hb + (size_t)ed * DD + c * 8);
        bf16x8 a3 = *(const bf16x8*)(hb + (size_t)ed * DD + 32 + c * 8);
        bf16x8 a4 = *(const bf16x8*)(rbfb + (size_t)(e0 + r) * 32 + c * 8);

        f32x4 accI[4], accU[4];
#pragma unroll
        for (int nf = 0; nf < 4; ++nf) {
            f32x4 z4 = {0.f, 0.f, 0.f, 0.f};
            accI[nf] = z4; accU[nf] = z4;
        }
#pragma unroll
        for (int kt = 0; kt < 5; ++kt) {
            bf16x8 a = (kt == 0) ? a0 : (kt == 1) ? a1 : (kt == 2) ? a2 : (kt == 3) ? a3 : a4;
#pragma unroll
            for (int nf = 0; nf < 4; ++nf) {
                bf16x8 bI = WfS[(kt * 4 + nf) * 64 + lane];
                accI[nf] = __builtin_amdgcn_mfma_f32_16x16x32_bf16(a, bI, accI[nf], 0, 0, 0);
                bf16x8 bU = WfS[1280 + (kt * 4 + nf) * 64 + lane];
                accU[nf] = __builtin_amdgcn_mfma_f32_16x16x32_bf16(a, bU, accU[nf], 0, 0, 0);
            }
        }
        // epilogue: D[row=(c*4+j)][col=nf*16+r]
#pragma unroll
        for (int nf = 0; nf < 4; ++nf) {
#pragma unroll
            for (int j = 0; j < 4; ++j) {
                const size_t o = (size_t)(e0 + c * 4 + j) * DD + nf * 16 + r;
                float vI = accI[nf][j];
                float vU = accU[nf][j];
                preI[o] = vI;
                preU[o] = vU;
                sI[nf] += vI; qI[nf] += vI * vI;
                sU[nf] += vU; qU[nf] += vU * vU;
            }
        }
    }

    // reduce stats across the 4 row-groups (lanes sharing lane&15), then atomics
#pragma unroll
    for (int nf = 0; nf < 4; ++nf) {
        float v;
        v = sI[nf]; v += __shfl_xor(v, 16, 64); v += __shfl_xor(v, 32, 64);
        if (lane < 16) unsafeAtomicAdd(&stats[nf * 16 + lane], v);
        v = qI[nf]; v += __shfl_xor(v, 16, 64); v += __shfl_xor(v, 32, 64);
        if (lane < 16) unsafeAtomicAdd(&stats[64 + nf * 16 + lane], v);
        v = sU[nf]; v += __shfl_xor(v, 16, 64); v += __shfl_xor(v, 32, 64);
        if (lane < 16) unsafeAtomicAdd(&stats[128 + nf * 16 + lane], v);
        v = qU[nf]; v += __shfl_xor(v, 16, 64); v += __shfl_xor(v, 32, 64);
        if (lane < 16) unsafeAtomicAdd(&stats[192 + nf * 16 + lane], v);
    }
}

// ---------------- finalize BN coefficients for gate/update ----------------
__global__ void fin_iu_k(const float* __restrict__ stats,
                         const float* __restrict__ gi, const float* __restrict__ bbi,
                         const float* __restrict__ gu, const float* __restrict__ bbu,
                         float* __restrict__ coeff) {
    int j = threadIdx.x; // 64
    const float invE = 1.f / (float)NE;
    float muI = stats[j] * invE;
    float varI = stats[64 + j] * invE - muI * muI;
    float sI = gi[j] * rsqrtf(varI + 1e-5f);
    coeff[j] = sI;
    coeff[64 + j] = bbi[j] - muI * sI;
    float muU = stats[128 + j] * invE;
    float varU = stats[192 + j] * invE - muU * muU;
    float sU = gu[j] * rsqrtf(varU + 1e-5f);
    coeff[128 + j] = sU;
    coeff[192 + j] = bbu[j] - muU * sU;
}

// ---------------- apply gate/update + CSR segment sum into m, + m column stats ----------------
__global__ __launch_bounds__(256) void apply_csr_k(const float* __restrict__ preI,
                                                   const float* __restrict__ preU,
                                                   const float* __restrict__ coeff,
                                                   const int* __restrict__ off,
                                                   const int* __restrict__ lst,
                                                   float* __restrict__ m,
                                                   float* __restrict__ msum,
                                                   float* __restrict__ msq) {
    int lane = threadIdx.x & 63;
    int wid = (blockIdx.x * blockDim.x + threadIdx.x) >> 6;
    int nw = (gridDim.x * blockDim.x) >> 6;
    float sI = coeff[lane], tI = coeff[64 + lane];
    float sU = coeff[128 + lane], tU = coeff[192 + lane];
    float accS = 0.f, accQ = 0.f;
    for (int n = wid; n < NN; n += nw) {
        int b = off[n], e = off[n + 1];
        float acc = 0.f;
        for (int i = b; i < e; ++i) {
            int eid = lst[i];
            float xi = preI[(size_t)eid * DD + lane] * sI + tI;
            float xu = preU[(size_t)eid * DD + lane] * sU + tU;
            acc += sig_(xi) * sp_(xu);
        }
        m[(size_t)n * DD + lane] = acc;
        accS += acc;
        accQ += acc * acc;
    }
    unsafeAtomicAdd(&msum[lane], accS);
    unsafeAtomicAdd(&msq[lane], accQ);
}

__global__ void fin_n_k(const float* __restrict__ msum, const float* __restrict__ msq,
                        const float* __restrict__ gn, const float* __restrict__ bbn,
                        float* __restrict__ coeffN) {
    int j = threadIdx.x; // 64
    const float invN = 1.f / (float)NN;
    float mu = msum[j] * invN;
    float var = msq[j] * invN - mu * mu;
    float s = gn[j] * rsqrtf(var + 1e-5f);
    coeffN[j] = s;
    coeffN[64 + j] = bbn[j] - mu * s;
}

// ---------------- h = sp(h + bn(m)) (fp32 + bf16 copy) ----------------
__global__ void h_update_k(float* __restrict__ h, unsigned short* __restrict__ hb,
                           const float* __restrict__ m,
                           const float* __restrict__ coeffN) {
    int i = blockIdx.x * 256 + threadIdx.x;
    if (i >= NN * DD) return;
    int j = i & 63;
    float v = h[i] + m[i] * coeffN[j] + coeffN[64 + j];
    v = sp_(v);
    h[i] = v;
    hb[i] = f2b(v);
}

// ---------------- pooling ----------------
__global__ void pool_k(const float* __restrict__ h, const int* __restrict__ gid,
                       float* __restrict__ pool) {
    int i = blockIdx.x * 256 + threadIdx.x;
    if (i >= NN * DD) return;
    int n = i >> 6;
    unsafeAtomicAdd(&pool[(size_t)gid[n] * DD + (i & 63)], h[i]);
}

__global__ void cnt_graph_k(const int* __restrict__ gid, float* __restrict__ pcnt) {
    int n = blockIdx.x * 256 + threadIdx.x;
    if (n < NN) unsafeAtomicAdd(&pcnt[gid[n]], 1.f);
}

// ---------------- head: sp, fc+sp, sp, out ----------------
__global__ __launch_bounds__(128) void head_k(const float* __restrict__ pool,
                                              const float* __restrict__ pcnt,
                                              const float* __restrict__ fcW,
                                              const float* __restrict__ fcb,
                                              const float* __restrict__ oW,
                                              const float* __restrict__ ob,
                                              float* __restrict__ out) {
    int g = blockIdx.x;
    int t = threadIdx.x; // 128
    __shared__ float feats[DD];
    __shared__ float red[FF];
    if (t < DD) {
        float c = fmaxf(pcnt[g], 1.f);
        feats[t] = sp_(pool[(size_t)g * DD + t] / c);
    }
    __syncthreads();
    float a = fcb[t];
#pragma unroll 1
    for (int j = 0; j < DD; ++j) a += feats[j] * fcW[j * FF + t];
    float y = sp_(sp_(a));
    red[t] = y * oW[t];
    __syncthreads();
    for (int s2 = 64; s2 >= 1; s2 >>= 1) {
        if (t < s2) red[t] += red[t + s2];
        __syncthreads();
    }
    if (t == 0) out[g] = red[0] + ob[0];
}

extern "C" void kernel_launch(void* const* d_in, const int* in_sizes, int n_in,
                              void* d_out, int out_size, void* d_ws, size_t ws_size,
                              hipStream_t stream) {
    const float* af   = (const float*)d_in[0];
    const float* bond = (const float*)d_in[1];
    const int*   src  = (const int*)d_in[2];
    const int*   dst  = (const int*)d_in[3];
    const int*   gid  = (const int*)d_in[4];
    const float* embW = (const float*)d_in[5];
    const float* embB = (const float*)d_in[6];
    const float* Wi   = (const float*)d_in[7];
    const float* gi   = (const float*)d_in[9];
    const float* bbi  = (const float*)d_in[10];
    const float* Wu   = (const float*)d_in[11];
    const float* gu   = (const float*)d_in[13];
    const float* bbu  = (const float*)d_in[14];
    const float* gn   = (const float*)d_in[15];
    const float* bbn  = (const float*)d_in[16];
    const float* fcW  = (const float*)d_in[17];
    const float* fcb  = (const float*)d_in[18];
    const float* oW   = (const float*)d_in[19];
    const float* ob   = (const float*)d_in[20];
    float* out = (float*)d_out;

    char* ws = (char*)d_ws;
    size_t off = 0;
    auto take = [&](size_t bytes) {
        size_t o = off;
        off += (bytes + 255) & ~(size_t)255;
        return o;
    };
    float* h     = (float*)(ws + take((size_t)NN * DD * 4));
    float* m     = (float*)(ws + take((size_t)NN * DD * 4));
    float* preI  = (float*)(ws + take((size_t)NE * DD * 4));
    float* preU  = (float*)(ws + take((size_t)NE * DD * 4));
    float* stats = (float*)(ws + take(512 * 4));
    float* coeff = (float*)(ws + take(512 * 4));
    float* pool  = (float*)(ws + take((size_t)NG * DD * 4)); // 32768 B
    float* pcnt  = (float*)(ws + take((size_t)NG * 4));      // 512 B padded
    int* ecount  = (int*)(ws + take((size_t)NN * 4));
    int* eoff    = (int*)(ws + take((size_t)(NN + 1) * 4));
    int* ecur    = (int*)(ws + take((size_t)NN * 4));
    int* elist   = (int*)(ws + take((size_t)NE * 4));
    unsigned short* hb   = (unsigned short*)(ws + take((size_t)NN * DD * 2));
    unsigned short* rbfb = (unsigned short*)(ws + take((size_t)NE * 32 * 2));
    unsigned short* Wf   = (unsigned short*)(ws + take((size_t)6 * 10240 * 2));

    // zero: pool (32768) + pcnt (512 incl pad) + ecount (80000) — contiguous
    hipMemsetAsync((void*)pool, 0, 32768 + 512 + (size_t)NN * 4, stream);

    prep_wf_k<<<6, 256, 0, stream>>>(Wi, Wu, Wf);
    rbf_k<<<(NE + 255) / 256, 256, 0, stream>>>(bond, rbfb);
    embed_k<<<(NN + 255) / 256, 256, 0, stream>>>(af, embW, embB, h, hb);

    cnt_edges_k<<<(NE + 255) / 256, 256, 0, stream>>>(dst, ecount);
    csr_scan_k<<<1, 1024, 0, stream>>>(ecount, eoff, ecur);
    fill_edges_k<<<(NE + 255) / 256, 256, 0, stream>>>(dst, ecur, elist);

    for (int l = 0; l < 3; ++l) {
        hipMemsetAsync((void*)stats, 0, 384 * 4, stream);
        edge_mfma_k<<<1024, 256, 0, stream>>>(hb, rbfb, Wf + (size_t)l * 2 * 10240, src, dst,
                                              preI, preU, stats);
        fin_iu_k<<<1, 64, 0, stream>>>(stats, gi + l * DD, bbi + l * DD, gu + l * DD, bbu + l * DD,
                                       coeff);
        apply_csr_k<<<1024, 256, 0, stream>>>(preI, preU, coeff, eoff, elist, m, stats + 256,
                                              stats + 320);
        fin_n_k<<<1, 64, 0, stream>>>(stats + 256, stats + 320, gn + l * DD, bbn + l * DD,
                                      coeff + 256);
        h_update_k<<<(NN * DD + 255) / 256, 256, 0, stream>>>(h, hb, m, coeff + 256);
    }

    pool_k<<<(NN * DD + 255) / 256, 256, 0, stream>>>(h, gid, pool);
    cnt_graph_k<<<(NN + 255) / 256, 256, 0, stream>>>(gid, pcnt);
    head_k<<<NG, 128, 0, stream>>>(pool, pcnt, fcW, fcb, oW, ob, out);
}

// Round 3
// 1013.504 us; speedup vs baseline: 7.6274x; 1.1215x over previous
//
#include <hip/hip_runtime.h>
#include <hip/hip_bf16.h>
#include <math.h>

#define NN 20000
#define NE 320000
#define NG 128
#define DD 64
#define FA 92
#define FF 128

typedef __attribute__((ext_vector_type(8))) short bf16x8;
typedef __attribute__((ext_vector_type(4))) float f32x4;

__device__ __forceinline__ float sp_(float x) {
    // softplus: max(x,0) + log(1 + exp(-|x|)); __logf ok since arg in (1,2]
    return fmaxf(x, 0.f) + __logf(1.f + __expf(-fabsf(x)));
}
__device__ __forceinline__ float sig_(float x) {
    return 1.f / (1.f + __expf(-x));
}
__device__ __forceinline__ unsigned short f2b(float x) {
    __hip_bfloat16 b = __float2bfloat16(x);
    return *reinterpret_cast<unsigned short*>(&b);
}

// ---------------- embedding: h = af @ emb_W + emb_b (fp32 + bf16 copy) ----------------
__global__ __launch_bounds__(256) void embed_k(const float* __restrict__ af,
                                               const float* __restrict__ W,
                                               const float* __restrict__ b,
                                               float* __restrict__ h,
                                               unsigned short* __restrict__ hb) {
    __shared__ float Ws[FA * DD]; // 23552 B
    for (int i = threadIdx.x * 4; i < FA * DD; i += 256 * 4)
        *(float4*)&Ws[i] = *(const float4*)&W[i];
    __syncthreads();
    int n = blockIdx.x * 256 + threadIdx.x;
    if (n >= NN) return;
    float acc[DD];
#pragma unroll
    for (int j = 0; j < DD; ++j) acc[j] = b[j];
    const float* row = af + (size_t)n * FA;
#pragma unroll 1
    for (int k4 = 0; k4 < FA / 4; ++k4) {
        float4 z = *(const float4*)(row + k4 * 4);
#pragma unroll
        for (int kk = 0; kk < 4; ++kk) {
            float a = ((const float*)&z)[kk];
            const float* wr = &Ws[(k4 * 4 + kk) * DD];
#pragma unroll
            for (int j = 0; j < DD; j += 4) {
                float4 w = *(const float4*)(wr + j);
                acc[j + 0] += a * w.x; acc[j + 1] += a * w.y;
                acc[j + 2] += a * w.z; acc[j + 3] += a * w.w;
            }
        }
    }
    float* o = h + (size_t)n * DD;
    unsigned short* ob = hb + (size_t)n * DD;
#pragma unroll
    for (int j = 0; j < DD; j += 4) {
        float4 v; v.x = acc[j]; v.y = acc[j + 1]; v.z = acc[j + 2]; v.w = acc[j + 3];
        *(float4*)(o + j) = v;
    }
#pragma unroll
    for (int j = 0; j < DD; ++j) ob[j] = f2b(acc[j]);
}

// ---------------- RBF bf16 precompute: rbfb[e][32] ----------------
__global__ void rbf_k(const float* __restrict__ bond, unsigned short* __restrict__ rbfb) {
    int e = blockIdx.x * 256 + threadIdx.x;
    if (e >= NE) return;
    float d = bond[e];
    unsigned short tmp[32];
#pragma unroll
    for (int k = 0; k < 32; ++k) {
        float c = (float)k * (8.0f / 31.0f);
        float u = d - c;
        tmp[k] = f2b(__expf(-3.875f * u * u));
    }
#pragma unroll
    for (int q = 0; q < 4; ++q)
        *(bf16x8*)&rbfb[(size_t)e * 32 + q * 8] = *(const bf16x8*)&tmp[q * 8];
}

// ---------------- weight fragment prep: Wf[l][g][kt][nf][lane][i] bf16 ----------------
// element = W[k = kt*32 + 8*(lane>>4) + i][col = nf*16 + (lane&15)]
__global__ void prep_wf_k(const float* __restrict__ Wi, const float* __restrict__ Wu,
                          unsigned short* __restrict__ Wf) {
    int b = blockIdx.x;          // 0..5 : layer*2 + gate
    int l = b >> 1, g = b & 1;
    const float* W = (g ? Wu : Wi) + (size_t)l * 160 * DD;
    for (int f = threadIdx.x; f < 10240; f += 256) {
        int i = f & 7;
        int lane = (f >> 3) & 63;
        int nf = (f >> 9) & 3;
        int kt = f >> 11;
        int k = kt * 32 + 8 * (lane >> 4) + i;
        int col = nf * 16 + (lane & 15);
        Wf[(size_t)b * 10240 + f] = f2b(W[k * DD + col]);
    }
}

// ---------------- CSR build ----------------
__global__ void cnt_edges_k(const int* __restrict__ dst, int* __restrict__ cnt) {
    int e = blockIdx.x * 256 + threadIdx.x;
    if (e < NE) atomicAdd(&cnt[dst[e]], 1);
}

__global__ __launch_bounds__(1024) void csr_scan_k(const int* __restrict__ cnt,
                                                   int* __restrict__ off,
                                                   int* __restrict__ cur) {
    __shared__ int part[1024];
    int t = threadIdx.x;
    int base = t * 20;
    int s = 0;
    for (int i = 0; i < 20; ++i) { int idx = base + i; if (idx < NN) s += cnt[idx]; }
    part[t] = s;
    __syncthreads();
    for (int ofs = 1; ofs < 1024; ofs <<= 1) {
        int v = (t >= ofs) ? part[t - ofs] : 0;
        __syncthreads();
        part[t] += v;
        __syncthreads();
    }
    int run = (t == 0) ? 0 : part[t - 1];
    for (int i = 0; i < 20; ++i) {
        int idx = base + i;
        if (idx < NN) { off[idx] = run; cur[idx] = run; run += cnt[idx]; }
    }
    if (t == 1023) off[NN] = run;
}

__global__ void fill_edges_k(const int* __restrict__ dst, int* __restrict__ cur,
                             int* __restrict__ lst) {
    int e = blockIdx.x * 256 + threadIdx.x;
    if (e < NE) {
        int p = atomicAdd(&cur[dst[e]], 1);
        lst[p] = e;
    }
}

// ---------------- pass 1: edge-tiled MFMA, column stats only (no pre stores) ----------------
__global__ __launch_bounds__(256) void edge_stats_k(const unsigned short* __restrict__ hb,
                                                    const unsigned short* __restrict__ rbfb,
                                                    const unsigned short* __restrict__ Wf,
                                                    const int* __restrict__ src,
                                                    const int* __restrict__ dst,
                                                    float* __restrict__ stats) {
    __shared__ bf16x8 WfS[2560]; // 40960 B : [gate][kt][nf][lane]
    {
        const bf16x8* Wf8 = (const bf16x8*)Wf;
        for (int i = threadIdx.x; i < 2560; i += 256) WfS[i] = Wf8[i];
    }
    __syncthreads();

    const int lane = threadIdx.x & 63;
    const int r = lane & 15;   // A row within tile / D col
    const int c = lane >> 4;   // k-chunk / D row group
    const int wid = (blockIdx.x * 256 + threadIdx.x) >> 6;
    const int nwaves = (gridDim.x * 256) >> 6;

    float sI[4] = {0.f, 0.f, 0.f, 0.f}, qI[4] = {0.f, 0.f, 0.f, 0.f};
    float sU[4] = {0.f, 0.f, 0.f, 0.f}, qU[4] = {0.f, 0.f, 0.f, 0.f};

    for (int tile = wid; tile < NE / 16; tile += nwaves) {
        const int e0 = tile * 16;
        const int es = src[e0 + r];
        const int ed = dst[e0 + r];

        bf16x8 a0 = *(const bf16x8*)(hb + (size_t)es * DD + c * 8);
        bf16x8 a1 = *(const bf16x8*)(hb + (size_t)es * DD + 32 + c * 8);
        bf16x8 a2 = *(const bf16x8*)(hb + (size_t)ed * DD + c * 8);
        bf16x8 a3 = *(const bf16x8*)(hb + (size_t)ed * DD + 32 + c * 8);
        bf16x8 a4 = *(const bf16x8*)(rbfb + (size_t)(e0 + r) * 32 + c * 8);

        f32x4 accI[4], accU[4];
#pragma unroll
        for (int nf = 0; nf < 4; ++nf) {
            f32x4 z4 = {0.f, 0.f, 0.f, 0.f};
            accI[nf] = z4; accU[nf] = z4;
        }
#pragma unroll
        for (int kt = 0; kt < 5; ++kt) {
            bf16x8 a = (kt == 0) ? a0 : (kt == 1) ? a1 : (kt == 2) ? a2 : (kt == 3) ? a3 : a4;
#pragma unroll
            for (int nf = 0; nf < 4; ++nf) {
                bf16x8 bI = WfS[(kt * 4 + nf) * 64 + lane];
                accI[nf] = __builtin_amdgcn_mfma_f32_16x16x32_bf16(a, bI, accI[nf], 0, 0, 0);
                bf16x8 bU = WfS[1280 + (kt * 4 + nf) * 64 + lane];
                accU[nf] = __builtin_amdgcn_mfma_f32_16x16x32_bf16(a, bU, accU[nf], 0, 0, 0);
            }
        }
#pragma unroll
        for (int nf = 0; nf < 4; ++nf) {
#pragma unroll
            for (int j = 0; j < 4; ++j) {
                float vI = accI[nf][j];
                float vU = accU[nf][j];
                sI[nf] += vI; qI[nf] += vI * vI;
                sU[nf] += vU; qU[nf] += vU * vU;
            }
        }
    }

#pragma unroll
    for (int nf = 0; nf < 4; ++nf) {
        float v;
        v = sI[nf]; v += __shfl_xor(v, 16, 64); v += __shfl_xor(v, 32, 64);
        if (lane < 16) unsafeAtomicAdd(&stats[nf * 16 + lane], v);
        v = qI[nf]; v += __shfl_xor(v, 16, 64); v += __shfl_xor(v, 32, 64);
        if (lane < 16) unsafeAtomicAdd(&stats[64 + nf * 16 + lane], v);
        v = sU[nf]; v += __shfl_xor(v, 16, 64); v += __shfl_xor(v, 32, 64);
        if (lane < 16) unsafeAtomicAdd(&stats[128 + nf * 16 + lane], v);
        v = qU[nf]; v += __shfl_xor(v, 16, 64); v += __shfl_xor(v, 32, 64);
        if (lane < 16) unsafeAtomicAdd(&stats[192 + nf * 16 + lane], v);
    }
}

// ---------------- finalize BN coefficients for gate/update; zero m-stats ----------------
__global__ void fin_iu_k(float* __restrict__ stats,
                         const float* __restrict__ gi, const float* __restrict__ bbi,
                         const float* __restrict__ gu, const float* __restrict__ bbu,
                         float* __restrict__ coeff) {
    int j = threadIdx.x; // 64
    const float invE = 1.f / (float)NE;
    float muI = stats[j] * invE;
    float varI = stats[64 + j] * invE - muI * muI;
    float sI = gi[j] * rsqrtf(varI + 1e-5f);
    coeff[j] = sI;
    coeff[64 + j] = bbi[j] - muI * sI;
    float muU = stats[128 + j] * invE;
    float varU = stats[192 + j] * invE - muU * muU;
    float sU = gu[j] * rsqrtf(varU + 1e-5f);
    coeff[128 + j] = sU;
    coeff[192 + j] = bbu[j] - muU * sU;
    stats[256 + j] = 0.f;  // msum
    stats[320 + j] = 0.f;  // msq
}

// ---------------- pass 2: wave-per-node MFMA recompute + BN + act + rowsum -> m ----------------
__global__ __launch_bounds__(256) void node_apply_k(const unsigned short* __restrict__ hb,
                                                    const unsigned short* __restrict__ rbfb,
                                                    const unsigned short* __restrict__ Wf,
                                                    const int* __restrict__ src,
                                                    const int* __restrict__ eoff,
                                                    const int* __restrict__ elist,
                                                    const float* __restrict__ coeff,
                                                    float* __restrict__ m,
                                                    float* __restrict__ msum,
                                                    float* __restrict__ msq) {
    __shared__ bf16x8 WfS[2560]; // 40 KB
    {
        const bf16x8* Wf8 = (const bf16x8*)Wf;
        for (int i = threadIdx.x; i < 2560; i += 256) WfS[i] = Wf8[i];
    }
    __syncthreads();

    const int lane = threadIdx.x & 63;
    const int r = lane & 15;
    const int c = lane >> 4;
    const int wid = (blockIdx.x * 256 + threadIdx.x) >> 6;
    const int nwaves = (gridDim.x * 256) >> 6;

    float sI[4], tI[4], sU[4], tU[4];
#pragma unroll
    for (int nf = 0; nf < 4; ++nf) {
        sI[nf] = coeff[nf * 16 + r];
        tI[nf] = coeff[64 + nf * 16 + r];
        sU[nf] = coeff[128 + nf * 16 + r];
        tU[nf] = coeff[192 + nf * 16 + r];
    }

    float accS = 0.f, accQ = 0.f;

    for (int n = wid; n < NN; n += nwaves) {
        const int b = eoff[n];
        const int cnt = eoff[n + 1] - b;
        float colacc[4] = {0.f, 0.f, 0.f, 0.f};

        // dst operand rows: all 16 rows are node n (wave-shared loads)
        bf16x8 a2 = *(const bf16x8*)(hb + (size_t)n * DD + c * 8);
        bf16x8 a3 = *(const bf16x8*)(hb + (size_t)n * DD + 32 + c * 8);

        for (int t = 0; t < cnt; t += 16) {
            int idx = t + r;
            int eid = elist[b + (idx < cnt ? idx : cnt - 1)];
            int es = src[eid];
            bf16x8 a0 = *(const bf16x8*)(hb + (size_t)es * DD + c * 8);
            bf16x8 a1 = *(const bf16x8*)(hb + (size_t)es * DD + 32 + c * 8);
            bf16x8 a4 = *(const bf16x8*)(rbfb + (size_t)eid * 32 + c * 8);

            f32x4 accI[4], accU[4];
#pragma unroll
            for (int nf = 0; nf < 4; ++nf) {
                f32x4 z4 = {0.f, 0.f, 0.f, 0.f};
                accI[nf] = z4; accU[nf] = z4;
            }
#pragma unroll
            for (int kt = 0; kt < 5; ++kt) {
                bf16x8 a = (kt == 0) ? a0 : (kt == 1) ? a1 : (kt == 2) ? a2 : (kt == 3) ? a3 : a4;
#pragma unroll
                for (int nf = 0; nf < 4; ++nf) {
                    bf16x8 bI = WfS[(kt * 4 + nf) * 64 + lane];
                    accI[nf] = __builtin_amdgcn_mfma_f32_16x16x32_bf16(a, bI, accI[nf], 0, 0, 0);
                    bf16x8 bU = WfS[1280 + (kt * 4 + nf) * 64 + lane];
                    accU[nf] = __builtin_amdgcn_mfma_f32_16x16x32_bf16(a, bU, accU[nf], 0, 0, 0);
                }
            }
            // D row = c*4+j (edge t + c*4+j), col = nf*16+r; activation + masked row-sum
#pragma unroll
            for (int nf = 0; nf < 4; ++nf) {
#pragma unroll
                for (int j = 0; j < 4; ++j) {
                    float xi = accI[nf][j] * sI[nf] + tI[nf];
                    float xu = accU[nf][j] * sU[nf] + tU[nf];
                    float act = sig_(xi) * sp_(xu);
                    if (t + c * 4 + j < cnt) colacc[nf] += act;
                }
            }
        }
        // reduce rows across the 4 c-groups: total column sums
#pragma unroll
        for (int nf = 0; nf < 4; ++nf) {
            colacc[nf] += __shfl_xor(colacc[nf], 16, 64);
            colacc[nf] += __shfl_xor(colacc[nf], 32, 64);
        }
        float val = colacc[c]; // this lane's column = c*16 + r
        m[(size_t)n * DD + c * 16 + r] = val;
        accS += val;
        accQ += val * val;
    }

    unsafeAtomicAdd(&msum[c * 16 + r], accS);
    unsafeAtomicAdd(&msq[c * 16 + r], accQ);
}

// ---------------- finalize BN(m) coeffs; zero edge-stats for next layer ----------------
__global__ void fin_n_k(float* __restrict__ stats,
                        const float* __restrict__ gn, const float* __restrict__ bbn,
                        float* __restrict__ coeffN) {
    int j = threadIdx.x; // 64
    const float invN = 1.f / (float)NN;
    float mu = stats[256 + j] * invN;
    float var = stats[320 + j] * invN - mu * mu;
    float s = gn[j] * rsqrtf(var + 1e-5f);
    coeffN[j] = s;
    coeffN[64 + j] = bbn[j] - mu * s;
    stats[j] = 0.f;
    stats[64 + j] = 0.f;
    stats[128 + j] = 0.f;
    stats[192 + j] = 0.f;
}

// ---------------- h = sp(h + bn(m)) (fp32 + bf16 copy) ----------------
__global__ void h_update_k(float* __restrict__ h, unsigned short* __restrict__ hb,
                           const float* __restrict__ m,
                           const float* __restrict__ coeffN) {
    int i = blockIdx.x * 256 + threadIdx.x;
    if (i >= NN * DD) return;
    int j = i & 63;
    float v = h[i] + m[i] * coeffN[j] + coeffN[64 + j];
    v = sp_(v);
    h[i] = v;
    hb[i] = f2b(v);
}

// ---------------- pooling ----------------
__global__ void pool_k(const float* __restrict__ h, const int* __restrict__ gid,
                       float* __restrict__ pool) {
    int i = blockIdx.x * 256 + threadIdx.x;
    if (i >= NN * DD) return;
    int n = i >> 6;
    unsafeAtomicAdd(&pool[(size_t)gid[n] * DD + (i & 63)], h[i]);
}

__global__ void cnt_graph_k(const int* __restrict__ gid, float* __restrict__ pcnt) {
    int n = blockIdx.x * 256 + threadIdx.x;
    if (n < NN) unsafeAtomicAdd(&pcnt[gid[n]], 1.f);
}

// ---------------- head: sp, fc+sp, sp, out ----------------
__global__ __launch_bounds__(128) void head_k(const float* __restrict__ pool,
                                              const float* __restrict__ pcnt,
                                              const float* __restrict__ fcW,
                                              const float* __restrict__ fcb,
                                              const float* __restrict__ oW,
                                              const float* __restrict__ ob,
                                              float* __restrict__ out) {
    int g = blockIdx.x;
    int t = threadIdx.x; // 128
    __shared__ float feats[DD];
    __shared__ float red[FF];
    if (t < DD) {
        float c = fmaxf(pcnt[g], 1.f);
        feats[t] = sp_(pool[(size_t)g * DD + t] / c);
    }
    __syncthreads();
    float a = fcb[t];
#pragma unroll 1
    for (int j = 0; j < DD; ++j) a += feats[j] * fcW[j * FF + t];
    float y = sp_(sp_(a));
    red[t] = y * oW[t];
    __syncthreads();
    for (int s2 = 64; s2 >= 1; s2 >>= 1) {
        if (t < s2) red[t] += red[t + s2];
        __syncthreads();
    }
    if (t == 0) out[g] = red[0] + ob[0];
}

extern "C" void kernel_launch(void* const* d_in, const int* in_sizes, int n_in,
                              void* d_out, int out_size, void* d_ws, size_t ws_size,
                              hipStream_t stream) {
    const float* af   = (const float*)d_in[0];
    const float* bond = (const float*)d_in[1];
    const int*   src  = (const int*)d_in[2];
    const int*   dst  = (const int*)d_in[3];
    const int*   gid  = (const int*)d_in[4];
    const float* embW = (const float*)d_in[5];
    const float* embB = (const float*)d_in[6];
    const float* Wi   = (const float*)d_in[7];
    const float* gi   = (const float*)d_in[9];
    const float* bbi  = (const float*)d_in[10];
    const float* Wu   = (const float*)d_in[11];
    const float* gu   = (const float*)d_in[13];
    const float* bbu  = (const float*)d_in[14];
    const float* gn   = (const float*)d_in[15];
    const float* bbn  = (const float*)d_in[16];
    const float* fcW  = (const float*)d_in[17];
    const float* fcb  = (const float*)d_in[18];
    const float* oW   = (const float*)d_in[19];
    const float* ob   = (const float*)d_in[20];
    float* out = (float*)d_out;

    char* ws = (char*)d_ws;
    size_t off = 0;
    auto take = [&](size_t bytes) {
        size_t o = off;
        off += (bytes + 255) & ~(size_t)255;
        return o;
    };
    float* h     = (float*)(ws + take((size_t)NN * DD * 4));
    float* m     = (float*)(ws + take((size_t)NN * DD * 4));
    float* stats = (float*)(ws + take(512 * 4)); // [sumI,sqI,sumU,sqU | msum,msq]
    float* coeff = (float*)(ws + take(512 * 4)); // [sI,tI,sU,tU | sN,tN]
    float* pool  = (float*)(ws + take((size_t)NG * DD * 4)); // 32768 B
    float* pcnt  = (float*)(ws + take((size_t)NG * 4));      // 512 B padded
    int* ecount  = (int*)(ws + take((size_t)NN * 4));
    int* eoff    = (int*)(ws + take((size_t)(NN + 1) * 4));
    int* ecur    = (int*)(ws + take((size_t)NN * 4));
    int* elist   = (int*)(ws + take((size_t)NE * 4));
    unsigned short* hb   = (unsigned short*)(ws + take((size_t)NN * DD * 2));
    unsigned short* rbfb = (unsigned short*)(ws + take((size_t)NE * 32 * 2));
    unsigned short* Wf   = (unsigned short*)(ws + take((size_t)6 * 10240 * 2));

    // zero: pool (32768) + pcnt (512 incl pad) + ecount (80000) — contiguous
    hipMemsetAsync((void*)pool, 0, 32768 + 512 + (size_t)NN * 4, stream);
    hipMemsetAsync((void*)stats, 0, 384 * 4, stream); // layer-0 edge stats (+msum area)

    prep_wf_k<<<6, 256, 0, stream>>>(Wi, Wu, Wf);
    rbf_k<<<(NE + 255) / 256, 256, 0, stream>>>(bond, rbfb);
    embed_k<<<(NN + 255) / 256, 256, 0, stream>>>(af, embW, embB, h, hb);

    cnt_edges_k<<<(NE + 255) / 256, 256, 0, stream>>>(dst, ecount);
    csr_scan_k<<<1, 1024, 0, stream>>>(ecount, eoff, ecur);
    fill_edges_k<<<(NE + 255) / 256, 256, 0, stream>>>(dst, ecur, elist);

    for (int l = 0; l < 3; ++l) {
        const unsigned short* Wfl = Wf + (size_t)l * 2 * 10240;
        edge_stats_k<<<1024, 256, 0, stream>>>(hb, rbfb, Wfl, src, dst, stats);
        fin_iu_k<<<1, 64, 0, stream>>>(stats, gi + l * DD, bbi + l * DD, gu + l * DD, bbu + l * DD,
                                       coeff);
        node_apply_k<<<1024, 256, 0, stream>>>(hb, rbfb, Wfl, src, eoff, elist, coeff, m,
                                               stats + 256, stats + 320);
        fin_n_k<<<1, 64, 0, stream>>>(stats, gn + l * DD, bbn + l * DD, coeff + 256);
        h_update_k<<<(NN * DD + 255) / 256, 256, 0, stream>>>(h, hb, m, coeff + 256);
    }

    pool_k<<<(NN * DD + 255) / 256, 256, 0, stream>>>(h, gid, pool);
    cnt_graph_k<<<(NN + 255) / 256, 256, 0, stream>>>(gid, pcnt);
    head_k<<<NG, 128, 0, stream>>>(pool, pcnt, fcW, fcb, oW, ob, out);
}